// Round 13
// baseline (3842.693 us; speedup 1.0000x reference)
//
#include <hip/hip_runtime.h>
#include <hip/hip_bf16.h>

#define BB 64
#define TT 512
#define DD 1024
#define UU 1024

typedef __attribute__((ext_vector_type(8))) short short8;
typedef __attribute__((ext_vector_type(4))) float f32x4;
typedef unsigned long long ull;

static __device__ __forceinline__ unsigned short f2bf(float f) {
    unsigned int u = __float_as_uint(f);
    unsigned int r = (u + 0x7fffu + ((u >> 16) & 1u)) >> 16;   // RNE
    return (unsigned short)r;
}
static __device__ __forceinline__ float bf2f(unsigned short s) {
    return __uint_as_float(((unsigned int)s) << 16);
}
static __device__ __forceinline__ float fsig(float x) {
    return 1.0f / (1.0f + __expf(-x));
}
static __device__ __forceinline__ float ftanh(float x) {
    float e = __expf(-2.0f * fabsf(x));
    float r = (1.0f - e) / (1.0f + e);
    return __builtin_copysignf(r, x);
}

// ---------------------------------------------------------------------------
// Pack a logical (1024 x 4096) weight into MFMA B-fragment layout (see r2).
// ---------------------------------------------------------------------------
__global__ __launch_bounds__(256) void pack_w(
    const float* __restrict__ w0, const float* __restrict__ w1,
    const float* __restrict__ w2, const float* __restrict__ w3,
    short* __restrict__ out)
{
    int tid = blockIdx.x * 256 + threadIdx.x;
    int lane = tid & 63;
    int kb = (tid >> 6) & 31;
    int n16 = tid >> 11;
    int col = (n16 << 4) + (lane & 15);
    int g = col >> 10, u = col & 1023;
    const float* __restrict__ src = (g == 0) ? w0 : (g == 1) ? w1 : (g == 2) ? w2 : w3;
    int kbase = kb * 32 + ((lane >> 4) << 3);
    short8 p;
#pragma unroll
    for (int i = 0; i < 8; ++i) p[i] = (short)f2bf(src[(size_t)(kbase + i) * UU + u]);
    *reinterpret_cast<short8*>(out + (size_t)tid * 8) = p;
}

// ---------------------------------------------------------------------------
__global__ __launch_bounds__(256) void init_hbf(const float* __restrict__ h0,
                                                unsigned short* __restrict__ hb)
{
    int i = blockIdx.x * 256 + threadIdx.x;  // 65536
    hb[i] = f2bf(h0[i & (UU - 1)]);
}

// ---------------------------------------------------------------------------
// Phase 1: xw = x @ [fw|iw|cw|ow] + bias, MFMA bf16, bf16 output.
// Output layout: xw[t][ublk(64)][b(64)][g(4)][u16(16)]   (unchanged from r12)
// ---------------------------------------------------------------------------
__global__ __launch_bounds__(256) void gemm_xw(
    const float* __restrict__ x, const short* __restrict__ wpk,
    const float* __restrict__ fb, const float* __restrict__ ib,
    const float* __restrict__ cb, const float* __restrict__ ob,
    unsigned short* __restrict__ xw)
{
    __shared__ short As[128 * 40];
    __shared__ short Bs[8 * 512];

    const int tid = threadIdx.x;
    const int lane = tid & 63;
    const int wid = tid >> 6;
    const int wr = wid >> 1, wc = wid & 1;
    const int n0 = blockIdx.x << 7;
    const int m0 = blockIdx.y << 7;
    const int n16b = n0 >> 4;

    const int srow = tid >> 1;
    const int kh = tid & 1;
    const float* __restrict__ xrow = x + (size_t)(m0 + srow) * DD + kh * 16;
    const short* __restrict__ wsrc =
        wpk + ((size_t)(n16b + (tid >> 5)) * 32) * 512 + (size_t)(tid & 31) * 16;

    f32x4 acc[4][4];
#pragma unroll
    for (int i = 0; i < 4; ++i)
#pragma unroll
        for (int j = 0; j < 4; ++j) acc[i][j] = (f32x4){0.f, 0.f, 0.f, 0.f};

    const int aoff = (wr * 64 + (lane & 15)) * 40 + (lane >> 4) * 8;
    const int boff = (wc * 4) * 512 + lane * 8;

    for (int kb = 0; kb < 32; ++kb) {
        const float4* xp = reinterpret_cast<const float4*>(xrow + kb * 32);
        float4 v0 = xp[0], v1 = xp[1], v2 = xp[2], v3 = xp[3];
        short8 p0, p1;
        p0[0] = (short)f2bf(v0.x); p0[1] = (short)f2bf(v0.y);
        p0[2] = (short)f2bf(v0.z); p0[3] = (short)f2bf(v0.w);
        p0[4] = (short)f2bf(v1.x); p0[5] = (short)f2bf(v1.y);
        p0[6] = (short)f2bf(v1.z); p0[7] = (short)f2bf(v1.w);
        p1[0] = (short)f2bf(v2.x); p1[1] = (short)f2bf(v2.y);
        p1[2] = (short)f2bf(v2.z); p1[3] = (short)f2bf(v2.w);
        p1[4] = (short)f2bf(v3.x); p1[5] = (short)f2bf(v3.y);
        p1[6] = (short)f2bf(v3.z); p1[7] = (short)f2bf(v3.w);
        *reinterpret_cast<short8*>(&As[srow * 40 + kh * 16]) = p0;
        *reinterpret_cast<short8*>(&As[srow * 40 + kh * 16 + 8]) = p1;

        const short8* ws8 = reinterpret_cast<const short8*>(wsrc + (size_t)kb * 512);
        short8 b0v = ws8[0], b1v = ws8[1];
        *reinterpret_cast<short8*>(&Bs[tid * 16]) = b0v;
        *reinterpret_cast<short8*>(&Bs[tid * 16 + 8]) = b1v;
        __syncthreads();

        short8 af[4], bfr[4];
#pragma unroll
        for (int fi = 0; fi < 4; ++fi)
            af[fi] = *reinterpret_cast<const short8*>(&As[aoff + fi * 640]);
#pragma unroll
        for (int fj = 0; fj < 4; ++fj)
            bfr[fj] = *reinterpret_cast<const short8*>(&Bs[boff + fj * 512]);
#pragma unroll
        for (int fi = 0; fi < 4; ++fi)
#pragma unroll
            for (int fj = 0; fj < 4; ++fj)
                acc[fi][fj] = __builtin_amdgcn_mfma_f32_16x16x32_bf16(
                    af[fi], bfr[fj], acc[fi][fj], 0, 0, 0);
        __syncthreads();
    }

    const int g = n0 >> 10;
    const float* __restrict__ bias = (g == 0) ? fb : (g == 1) ? ib : (g == 2) ? cb : ob;
#pragma unroll
    for (int fi = 0; fi < 4; ++fi) {
#pragma unroll
        for (int fj = 0; fj < 4; ++fj) {
            int n = n0 + wc * 64 + fj * 16 + (lane & 15);
            int uc = n & 1023;
            int ub = uc >> 4, ul = uc & 15;
            float bv = bias[uc];
#pragma unroll
            for (int r = 0; r < 4; ++r) {
                int row = m0 + wr * 64 + fi * 16 + (lane >> 4) * 4 + r;
                int b = row >> 9, t = row & 511;
                float v = acc[fi][fj][r] + bv;
                size_t off = (((size_t)t * 64 + ub) * BB + b) * 64 + g * 16 + ul;
                xw[off] = f2bf(v);
            }
        }
    }
}

// ---------------------------------------------------------------------------
// Phase 2: persistent scan with PRODUCER/CONSUMER WAVE SPECIALIZATION.
// Grid 128 = 2 chain-pairs (z) x 64 u-blocks; block = 384 thr (6 waves):
//   waves 0-3 (gates):  spin hls-ready -> MFMA -> gbuf -> nx prefetch ->
//                       LDS mini-barrier -> tail -> hsh -> LDS counter
//   wave 4 = comms-A, wave 5 = comms-B: spin tail-counter -> read hsh ->
//                       sc1 store -> drain -> flag -> poll remote flags
//                       (data-dep addr) -> DMA hls <- hrot -> drain ->
//                       release hls-ready
// Cross-block dep chain runs in comms waves CONCURRENTLY with compute.
// No __syncthreads in the loop; LDS workgroup atomics only.
// ---------------------------------------------------------------------------
__global__ __launch_bounds__(384, 1) void lstm_scan(
    const unsigned short* __restrict__ xw, const float* __restrict__ h0,
    unsigned short* __restrict__ hrot,     // [TT+1][64][1024] bf16 rotating
    const short* __restrict__ upk,
    float* __restrict__ y, int* __restrict__ flg)   // [TT+1][4][64]
{
    __shared__ unsigned short hlsA[16 * 1032 + 8];
    __shared__ unsigned short hlsB[16 * 1032 + 8];
    __shared__ float gbufA[4][16][20];
    __shared__ float gbufB[4][16][20];
    __shared__ unsigned short hshA[16][16];
    __shared__ unsigned short hshB[16][16];
    __shared__ int cA1, cA2, cB1, cB2, rdyA, rdyB;

    const int tid = threadIdx.x;
    const int lane = tid & 63;
    const int wv = tid >> 6;              // 0..5
    const int z  = blockIdx.x >> 6;
    const int ub = blockIdx.x & 63;
    const int mzA = z * 2, mzB = z * 2 + 1;
    const int r0A = mzA << 4, r0B = mzB << 4;
    const int u0 = ub << 4;

    if (tid == 0) { cA1 = 0; cA2 = 0; cB1 = 0; cB2 = 0; rdyA = 0; rdyB = 0; }
    __syncthreads();   // counters visible to all 6 waves; roles diverge below

    if (wv < 4) {
        // =================== COMPUTE WAVES (gates) ===================
        const int gi = wv;
        const short* __restrict__ bsrc =
            upk + ((size_t)(gi * 64 + ub) * 32) * 512 + (size_t)lane * 8;
        short8 bfr[32];
#pragma unroll
        for (int kb = 0; kb < 32; ++kb)
            bfr[kb] = *reinterpret_cast<const short8*>(bsrc + (size_t)kb * 512);

        const int aoff = (lane & 15) * 1032 + (lane >> 4) * 8;
        const int trow = tid >> 4, tcol = tid & 15;

        float h_ownA = h0[u0 + tcol];
        float h_ownB = h_ownA;

        float xvA[4], xvB[4], nxA[4], nxB[4];
        {
            const unsigned short* xpA =
                xw + ((size_t)0 * 64 + ub) * 4096 + (size_t)(r0A + trow) * 64 + tcol;
            const unsigned short* xpB =
                xw + ((size_t)0 * 64 + ub) * 4096 + (size_t)(r0B + trow) * 64 + tcol;
#pragma unroll
            for (int g = 0; g < 4; ++g) {
                xvA[g] = bf2f(xpA[g * 16]);
                xvB[g] = bf2f(xpB[g * 16]);
            }
        }

        for (int t = 0; t < TT; ++t) {
            // ---------------- chain A ----------------
            while (__hip_atomic_load(&rdyA, __ATOMIC_ACQUIRE,
                                     __HIP_MEMORY_SCOPE_WORKGROUP) < t + 1)
                __builtin_amdgcn_s_sleep(1);

            f32x4 a0 = (f32x4){0.f, 0.f, 0.f, 0.f};
            f32x4 a1 = (f32x4){0.f, 0.f, 0.f, 0.f};
#pragma unroll
            for (int kg = 0; kg < 32; kg += 2) {
                short8 f0 = *reinterpret_cast<const short8*>(&hlsA[aoff + kg * 32]);
                short8 f1 = *reinterpret_cast<const short8*>(&hlsA[aoff + kg * 32 + 32]);
                a0 = __builtin_amdgcn_mfma_f32_16x16x32_bf16(f0, bfr[kg], a0, 0, 0, 0);
                a1 = __builtin_amdgcn_mfma_f32_16x16x32_bf16(f1, bfr[kg + 1], a1, 0, 0, 0);
            }
            a0[0] += a1[0]; a0[1] += a1[1]; a0[2] += a1[2]; a0[3] += a1[3];
#pragma unroll
            for (int r = 0; r < 4; ++r)
                gbufA[gi][(lane >> 4) * 4 + r][lane & 15] = a0[r];

            // xw(t+1) chain-A prefetch (independent; covers until next tail)
            if (t + 1 < TT) {
                const unsigned short* xpA = xw + ((size_t)(t + 1) * 64 + ub) * 4096
                                            + (size_t)(r0A + trow) * 64 + tcol;
#pragma unroll
                for (int g = 0; g < 4; ++g) nxA[g] = bf2f(xpA[g * 16]);
            }

            if (lane == 0)
                __hip_atomic_fetch_add(&cA1, 1, __ATOMIC_RELEASE,
                                       __HIP_MEMORY_SCOPE_WORKGROUP);
            while (__hip_atomic_load(&cA1, __ATOMIC_ACQUIRE,
                                     __HIP_MEMORY_SCOPE_WORKGROUP) < 4 * (t + 1)) {}

            {
                float gf  = gbufA[0][trow][tcol] + xvA[0];
                float gii = gbufA[1][trow][tcol] + xvA[1];
                float gc  = gbufA[2][trow][tcol] + xvA[2];
                float go  = gbufA[3][trow][tcol] + xvA[3];
                float h1  = fsig(gf) * h_ownA + fsig(gii) * ftanh(gc);
                h_ownA = h1;
                hshA[trow][tcol] = f2bf(h1);
                y[((size_t)(r0A + trow) * TT + t) * UU + u0 + tcol] =
                    fsig(go) * ftanh(h1);
            }
            if (lane == 0)
                __hip_atomic_fetch_add(&cA2, 1, __ATOMIC_RELEASE,
                                       __HIP_MEMORY_SCOPE_WORKGROUP);

            // ---------------- chain B ----------------
            while (__hip_atomic_load(&rdyB, __ATOMIC_ACQUIRE,
                                     __HIP_MEMORY_SCOPE_WORKGROUP) < t + 1)
                __builtin_amdgcn_s_sleep(1);

            f32x4 b0 = (f32x4){0.f, 0.f, 0.f, 0.f};
            f32x4 b1 = (f32x4){0.f, 0.f, 0.f, 0.f};
#pragma unroll
            for (int kg = 0; kg < 32; kg += 2) {
                short8 f0 = *reinterpret_cast<const short8*>(&hlsB[aoff + kg * 32]);
                short8 f1 = *reinterpret_cast<const short8*>(&hlsB[aoff + kg * 32 + 32]);
                b0 = __builtin_amdgcn_mfma_f32_16x16x32_bf16(f0, bfr[kg], b0, 0, 0, 0);
                b1 = __builtin_amdgcn_mfma_f32_16x16x32_bf16(f1, bfr[kg + 1], b1, 0, 0, 0);
            }
            b0[0] += b1[0]; b0[1] += b1[1]; b0[2] += b1[2]; b0[3] += b1[3];
#pragma unroll
            for (int r = 0; r < 4; ++r)
                gbufB[gi][(lane >> 4) * 4 + r][lane & 15] = b0[r];

            if (t + 1 < TT) {
                const unsigned short* xpB = xw + ((size_t)(t + 1) * 64 + ub) * 4096
                                            + (size_t)(r0B + trow) * 64 + tcol;
#pragma unroll
                for (int g = 0; g < 4; ++g) nxB[g] = bf2f(xpB[g * 16]);
            }

            if (lane == 0)
                __hip_atomic_fetch_add(&cB1, 1, __ATOMIC_RELEASE,
                                       __HIP_MEMORY_SCOPE_WORKGROUP);
            while (__hip_atomic_load(&cB1, __ATOMIC_ACQUIRE,
                                     __HIP_MEMORY_SCOPE_WORKGROUP) < 4 * (t + 1)) {}

            {
                float gf  = gbufB[0][trow][tcol] + xvB[0];
                float gii = gbufB[1][trow][tcol] + xvB[1];
                float gc  = gbufB[2][trow][tcol] + xvB[2];
                float go  = gbufB[3][trow][tcol] + xvB[3];
                float h1  = fsig(gf) * h_ownB + fsig(gii) * ftanh(gc);
                h_ownB = h1;
                hshB[trow][tcol] = f2bf(h1);
                y[((size_t)(r0B + trow) * TT + t) * UU + u0 + tcol] =
                    fsig(go) * ftanh(h1);
            }
            if (lane == 0)
                __hip_atomic_fetch_add(&cB2, 1, __ATOMIC_RELEASE,
                                       __HIP_MEMORY_SCOPE_WORKGROUP);

#pragma unroll
            for (int g = 0; g < 4; ++g) { xvA[g] = nxA[g]; xvB[g] = nxB[g]; }
        }
    } else {
        // =================== COMMS WAVES ===================
        const bool isA = (wv == 4);
        const int mz = isA ? mzA : mzB;
        const int r0 = mz << 4;
        unsigned short* hls = isA ? hlsA : hlsB;
        unsigned short (*hsh)[16] = isA ? hshA : hshB;
        int* c2  = isA ? &cA2 : &cB2;
        int* rdy = isA ? &rdyA : &rdyB;

        // prologue: stage slot 0 (init_hbf ran before this kernel)
        {
            const unsigned short* hc = hrot + (size_t)r0 * UU;
#pragma unroll
            for (int p = 0; p < 32; ++p) {
                int row = p >> 1, half = p & 1;
                __builtin_amdgcn_global_load_lds(
                    (const void*)(hc + (size_t)row * 1024 + half * 512 + (size_t)lane * 8),
                    (void*)&hls[row * 1032 + half * 512], 16, 0, 16);
            }
            asm volatile("s_waitcnt vmcnt(0)" ::: "memory");
            __hip_atomic_store(rdy, 1, __ATOMIC_RELEASE, __HIP_MEMORY_SCOPE_WORKGROUP);
        }

        for (int t = 0; t < TT - 1; ++t) {
            // wait for this step's tails (4 compute waves)
            while (__hip_atomic_load(c2, __ATOMIC_ACQUIRE,
                                     __HIP_MEMORY_SCOPE_WORKGROUP) < 4 * (t + 1))
                __builtin_amdgcn_s_sleep(1);

            // read h(t) tile from LDS, publish via sc1 stores
            {
                int row = lane >> 2, c4 = (lane & 3) << 2;
                ull pv = *reinterpret_cast<const ull*>(&hsh[row][c4]);
                unsigned short* dst = hrot + (size_t)(t + 1) * (BB * UU)
                                      + (size_t)(r0 + row) * UU + u0 + c4;
                __hip_atomic_store(reinterpret_cast<ull*>(dst), pv,
                                   __ATOMIC_RELAXED, __HIP_MEMORY_SCOPE_AGENT);
            }
            asm volatile("s_waitcnt vmcnt(0)" ::: "memory");
            if (lane == 0)
                __hip_atomic_store(flg + ((size_t)(t + 1) * 4 + mz) * 64 + ub, 1,
                                   __ATOMIC_RELAXED, __HIP_MEMORY_SCOPE_AGENT);

            // poll all 64 producers of this chain (lane = producer ub')
            int v;
            const int* fl = flg + ((size_t)(t + 1) * 4 + mz) * 64 + lane;
            do {
                v = __hip_atomic_load(fl, __ATOMIC_RELAXED, __HIP_MEMORY_SCOPE_AGENT);
                if (v == 0) __builtin_amdgcn_s_sleep(1);
            } while (v == 0);

            // DMA h(t+1) into hls; global addr data-depends on polled value
            // (v==1 -> offset 0) so the loads cannot be hoisted above the poll.
            const unsigned short* hc =
                hrot + (size_t)(t + 1) * (BB * UU) + (size_t)r0 * UU + (size_t)(v - 1);
#pragma unroll
            for (int p = 0; p < 32; ++p) {
                int row = p >> 1, half = p & 1;
                __builtin_amdgcn_global_load_lds(
                    (const void*)(hc + (size_t)row * 1024 + half * 512 + (size_t)lane * 8),
                    (void*)&hls[row * 1032 + half * 512], 16, 0, 16);
            }
            asm volatile("s_waitcnt vmcnt(0)" ::: "memory");
            __hip_atomic_store(rdy, t + 2, __ATOMIC_RELEASE,
                               __HIP_MEMORY_SCOPE_WORKGROUP);
        }
    }
}

// ---------------------------------------------------------------------------
extern "C" void kernel_launch(void* const* d_in, const int* in_sizes, int n_in,
                              void* d_out, int out_size, void* d_ws, size_t ws_size,
                              hipStream_t stream)
{
    const float* x  = (const float*)d_in[0];
    const float* fw = (const float*)d_in[1];
    const float* fu = (const float*)d_in[2];
    const float* fb = (const float*)d_in[3];
    const float* iw = (const float*)d_in[4];
    const float* iu = (const float*)d_in[5];
    const float* ib = (const float*)d_in[6];
    const float* cw = (const float*)d_in[7];
    const float* cu = (const float*)d_in[8];
    const float* cb = (const float*)d_in[9];
    const float* ow = (const float*)d_in[10];
    const float* ou = (const float*)d_in[11];
    const float* ob = (const float*)d_in[12];
    const float* h0 = (const float*)d_in[13];
    float* y = (float*)d_out;

    const size_t xw_elems = (size_t)TT * BB * 4 * UU;       // 134,217,728
    const size_t pk_elems = (size_t)4 * 1024 * 1024;        // shorts per packed W
    const size_t hrot_elems = (size_t)(TT + 1) * BB * UU;

    char* wsb = (char*)d_ws;
    unsigned short* xw = (unsigned short*)wsb;
    short* upk = (short*)(wsb + xw_elems * 2);
    short* wpk = upk + pk_elems;
    unsigned short* hrot = (unsigned short*)(wpk + pk_elems);
    int* flg = (int*)(hrot + hrot_elems);

    pack_w<<<2048, 256, 0, stream>>>(fu, iu, cu, ou, upk);
    pack_w<<<2048, 256, 0, stream>>>(fw, iw, cw, ow, wpk);
    init_hbf<<<256, 256, 0, stream>>>(h0, hrot);
    gemm_xw<<<dim3(32, 256), 256, 0, stream>>>(x, wpk, fb, ib, cb, ob, xw);
    hipMemsetAsync(flg, 0, (size_t)(TT + 1) * 4 * 64 * sizeof(int), stream);

    lstm_scan<<<128, 384, 0, stream>>>(xw, h0, hrot, upk, y, flg);
}

// Round 14
// 2444.093 us; speedup vs baseline: 1.5722x; 1.5722x over previous
//
#include <hip/hip_runtime.h>
#include <hip/hip_bf16.h>

#define BB 64
#define TT 512
#define DD 1024
#define UU 1024

typedef __attribute__((ext_vector_type(8))) short short8;
typedef __attribute__((ext_vector_type(4))) float f32x4;
typedef unsigned long long ull;

static __device__ __forceinline__ unsigned short f2bf(float f) {
    unsigned int u = __float_as_uint(f);
    unsigned int r = (u + 0x7fffu + ((u >> 16) & 1u)) >> 16;   // RNE
    return (unsigned short)r;
}
static __device__ __forceinline__ float bf2f(unsigned short s) {
    return __uint_as_float(((unsigned int)s) << 16);
}
static __device__ __forceinline__ float fsig(float x) {
    return 1.0f / (1.0f + __expf(-x));
}
static __device__ __forceinline__ float ftanh(float x) {
    float e = __expf(-2.0f * fabsf(x));
    float r = (1.0f - e) / (1.0f + e);
    return __builtin_copysignf(r, x);
}

// ---------------------------------------------------------------------------
// Pack a logical (1024 x 4096) weight into MFMA B-fragment layout (see r2).
// ---------------------------------------------------------------------------
__global__ __launch_bounds__(256) void pack_w(
    const float* __restrict__ w0, const float* __restrict__ w1,
    const float* __restrict__ w2, const float* __restrict__ w3,
    short* __restrict__ out)
{
    int tid = blockIdx.x * 256 + threadIdx.x;
    int lane = tid & 63;
    int kb = (tid >> 6) & 31;
    int n16 = tid >> 11;
    int col = (n16 << 4) + (lane & 15);
    int g = col >> 10, u = col & 1023;
    const float* __restrict__ src = (g == 0) ? w0 : (g == 1) ? w1 : (g == 2) ? w2 : w3;
    int kbase = kb * 32 + ((lane >> 4) << 3);
    short8 p;
#pragma unroll
    for (int i = 0; i < 8; ++i) p[i] = (short)f2bf(src[(size_t)(kbase + i) * UU + u]);
    *reinterpret_cast<short8*>(out + (size_t)tid * 8) = p;
}

// ---------------------------------------------------------------------------
__global__ __launch_bounds__(256) void init_hbf(const float* __restrict__ h0,
                                                unsigned short* __restrict__ hb)
{
    int i = blockIdx.x * 256 + threadIdx.x;  // 65536
    hb[i] = f2bf(h0[i & (UU - 1)]);
}

// ---------------------------------------------------------------------------
// Phase 1: xw = x @ [fw|iw|cw|ow] + bias, MFMA bf16, bf16 output.
// Output layout: xw[t][ublk(64)][b(64)][g(4)][u16(16)]
// ---------------------------------------------------------------------------
__global__ __launch_bounds__(256) void gemm_xw(
    const float* __restrict__ x, const short* __restrict__ wpk,
    const float* __restrict__ fb, const float* __restrict__ ib,
    const float* __restrict__ cb, const float* __restrict__ ob,
    unsigned short* __restrict__ xw)
{
    __shared__ short As[128 * 40];
    __shared__ short Bs[8 * 512];

    const int tid = threadIdx.x;
    const int lane = tid & 63;
    const int wid = tid >> 6;
    const int wr = wid >> 1, wc = wid & 1;
    const int n0 = blockIdx.x << 7;
    const int m0 = blockIdx.y << 7;
    const int n16b = n0 >> 4;

    const int srow = tid >> 1;
    const int kh = tid & 1;
    const float* __restrict__ xrow = x + (size_t)(m0 + srow) * DD + kh * 16;
    const short* __restrict__ wsrc =
        wpk + ((size_t)(n16b + (tid >> 5)) * 32) * 512 + (size_t)(tid & 31) * 16;

    f32x4 acc[4][4];
#pragma unroll
    for (int i = 0; i < 4; ++i)
#pragma unroll
        for (int j = 0; j < 4; ++j) acc[i][j] = (f32x4){0.f, 0.f, 0.f, 0.f};

    const int aoff = (wr * 64 + (lane & 15)) * 40 + (lane >> 4) * 8;
    const int boff = (wc * 4) * 512 + lane * 8;

    for (int kb = 0; kb < 32; ++kb) {
        const float4* xp = reinterpret_cast<const float4*>(xrow + kb * 32);
        float4 v0 = xp[0], v1 = xp[1], v2 = xp[2], v3 = xp[3];
        short8 p0, p1;
        p0[0] = (short)f2bf(v0.x); p0[1] = (short)f2bf(v0.y);
        p0[2] = (short)f2bf(v0.z); p0[3] = (short)f2bf(v0.w);
        p0[4] = (short)f2bf(v1.x); p0[5] = (short)f2bf(v1.y);
        p0[6] = (short)f2bf(v1.z); p0[7] = (short)f2bf(v1.w);
        p1[0] = (short)f2bf(v2.x); p1[1] = (short)f2bf(v2.y);
        p1[2] = (short)f2bf(v2.z); p1[3] = (short)f2bf(v2.w);
        p1[4] = (short)f2bf(v3.x); p1[5] = (short)f2bf(v3.y);
        p1[6] = (short)f2bf(v3.z); p1[7] = (short)f2bf(v3.w);
        *reinterpret_cast<short8*>(&As[srow * 40 + kh * 16]) = p0;
        *reinterpret_cast<short8*>(&As[srow * 40 + kh * 16 + 8]) = p1;

        const short8* ws8 = reinterpret_cast<const short8*>(wsrc + (size_t)kb * 512);
        short8 b0v = ws8[0], b1v = ws8[1];
        *reinterpret_cast<short8*>(&Bs[tid * 16]) = b0v;
        *reinterpret_cast<short8*>(&Bs[tid * 16 + 8]) = b1v;
        __syncthreads();

        short8 af[4], bfr[4];
#pragma unroll
        for (int fi = 0; fi < 4; ++fi)
            af[fi] = *reinterpret_cast<const short8*>(&As[aoff + fi * 640]);
#pragma unroll
        for (int fj = 0; fj < 4; ++fj)
            bfr[fj] = *reinterpret_cast<const short8*>(&Bs[boff + fj * 512]);
#pragma unroll
        for (int fi = 0; fi < 4; ++fi)
#pragma unroll
            for (int fj = 0; fj < 4; ++fj)
                acc[fi][fj] = __builtin_amdgcn_mfma_f32_16x16x32_bf16(
                    af[fi], bfr[fj], acc[fi][fj], 0, 0, 0);
        __syncthreads();
    }

    const int g = n0 >> 10;
    const float* __restrict__ bias = (g == 0) ? fb : (g == 1) ? ib : (g == 2) ? cb : ob;
#pragma unroll
    for (int fi = 0; fi < 4; ++fi) {
#pragma unroll
        for (int fj = 0; fj < 4; ++fj) {
            int n = n0 + wc * 64 + fj * 16 + (lane & 15);
            int uc = n & 1023;
            int ub = uc >> 4, ul = uc & 15;
            float bv = bias[uc];
#pragma unroll
            for (int r = 0; r < 4; ++r) {
                int row = m0 + wr * 64 + fi * 16 + (lane >> 4) * 4 + r;
                int b = row >> 9, t = row & 511;
                float v = acc[fi][fj][r] + bv;
                size_t off = (((size_t)t * 64 + ub) * BB + b) * 64 + g * 16 + ul;
                xw[off] = f2bf(v);
            }
        }
    }
}

// ---------------------------------------------------------------------------
// One phase of the pipelined two-chain scan (chain MZ computes step t; wave 1
// additionally polls+issues the DMA for chain OMZ's step POLL_T into OHLS).
// Barriers: one raw lgkm-only s_barrier (gbuf->tail; does NOT drain wave1's
// in-flight DMA) + one __syncthreads (drains stores AND wave1's DMA; its
// latency overlaps the tail). Flag fires after the full drain.
// ---------------------------------------------------------------------------
#define PHASE(MZ, R0, HLS, GBUF, HOWN, OMZ, OHLS, DO_POLL, POLL_T)                 \
  do {                                                                             \
    const unsigned short* __restrict__ xp =                                        \
        xw + ((size_t)t * 64 + ub) * 4096 + (size_t)((R0) + trow) * 64 + tcol;     \
    float xv0 = bf2f(xp[0]);                                                       \
    float xv1 = bf2f(xp[16]);                                                      \
    float xv2 = bf2f(xp[32]);                                                      \
    float xv3 = bf2f(xp[48]);                                                      \
    f32x4 acc0 = (f32x4){0.f, 0.f, 0.f, 0.f};                                      \
    f32x4 acc1 = (f32x4){0.f, 0.f, 0.f, 0.f};                                      \
    _Pragma("unroll")                                                              \
    for (int kg = 0; kg < 32; kg += 2) {                                           \
      short8 a0 = *reinterpret_cast<const short8*>(&HLS[aoff + kg * 32]);          \
      short8 a1 = *reinterpret_cast<const short8*>(&HLS[aoff + kg * 32 + 32]);     \
      acc0 = __builtin_amdgcn_mfma_f32_16x16x32_bf16(a0, bfr[kg], acc0, 0, 0, 0);  \
      acc1 = __builtin_amdgcn_mfma_f32_16x16x32_bf16(a1, bfr[kg + 1], acc1,        \
                                                     0, 0, 0);                     \
    }                                                                              \
    acc0[0] += acc1[0]; acc0[1] += acc1[1];                                        \
    acc0[2] += acc1[2]; acc0[3] += acc1[3];                                        \
    _Pragma("unroll")                                                              \
    for (int r = 0; r < 4; ++r)                                                    \
      GBUF[gi][(lane >> 4) * 4 + r][lane & 15] = acc0[r];                          \
    if (gi == 1 && (DO_POLL)) {                                                    \
      const int* fl = flg + ((size_t)(POLL_T) * 4 + (OMZ)) * 64 + lane;            \
      int v;                                                                       \
      do {                                                                         \
        v = __hip_atomic_load(fl, __ATOMIC_RELAXED, __HIP_MEMORY_SCOPE_AGENT);     \
        if (v == 0) __builtin_amdgcn_s_sleep(1);                                   \
      } while (v == 0);                                                            \
      asm volatile("" ::: "memory");                                               \
      const unsigned short* hc = hrot + (size_t)(POLL_T) * (BB * UU)               \
                                 + ((size_t)(OMZ) << 4) * UU + (size_t)(v - 1);    \
      _Pragma("unroll")                                                            \
      for (int p = 0; p < 32; ++p) {                                               \
        int row = p >> 1, half = p & 1;                                            \
        __builtin_amdgcn_global_load_lds(                                          \
            (const void*)(hc + (size_t)row * 1024 + half * 512 + (size_t)lane * 8),\
            (void*)&OHLS[row * 1032 + half * 512], 16, 0, 16);                     \
      }                                                                            \
    }                                                                              \
    asm volatile("s_waitcnt lgkmcnt(0)" ::: "memory");                             \
    __builtin_amdgcn_s_barrier();                                                  \
    asm volatile("" ::: "memory");                                                 \
    {                                                                              \
      float gf  = GBUF[0][trow][tcol] + xv0;                                       \
      float gii = GBUF[1][trow][tcol] + xv1;                                       \
      float gc  = GBUF[2][trow][tcol] + xv2;                                       \
      float go  = GBUF[3][trow][tcol] + xv3;                                       \
      float h1  = fsig(gf) * (HOWN) + fsig(gii) * ftanh(gc);                       \
      (HOWN) = h1;                                                                 \
      y[((size_t)((R0) + trow) * TT + t) * UU + u0 + tcol] = fsig(go) * ftanh(h1); \
      unsigned int hb16 = f2bf(h1);                                                \
      unsigned int n1 = __shfl_down(hb16, 1);                                      \
      unsigned int n2 = __shfl_down(hb16, 2);                                      \
      unsigned int n3 = __shfl_down(hb16, 3);                                      \
      if (t < TT - 1 && (lane & 3) == 0) {                                         \
        unsigned long long pv =                                                    \
            (unsigned long long)(hb16 | (n1 << 16)) |                              \
            ((unsigned long long)(n2 | (n3 << 16)) << 32);                         \
        unsigned short* dst = hrot + (size_t)(t + 1) * (BB * UU)                   \
                              + (size_t)((R0) + trow) * UU + u0 + tcol;            \
        __hip_atomic_store(reinterpret_cast<ull*>(dst), pv,                        \
                           __ATOMIC_RELAXED, __HIP_MEMORY_SCOPE_AGENT);            \
      }                                                                            \
    }                                                                              \
    __syncthreads();   /* drains h/y stores AND wave1's DMA; barrier */            \
    if (t < TT - 1 && gi == 0 && lane == 0)                                        \
      __hip_atomic_store(flg + ((size_t)(t + 1) * 4 + (MZ)) * 64 + ub, 1,          \
                         __ATOMIC_RELAXED, __HIP_MEMORY_SCOPE_AGENT);              \
  } while (0)

// ---------------------------------------------------------------------------
// Phase 2: persistent scan, two chains per block, alternating phases with
// CROSS-PHASE DMA PIPELINING. Grid 128 = 2 chain-pairs x 64 u-blocks;
// block = 4 waves (wave = gate, U B-frags in VGPRs).
//   phase A(t): MFMA_A -> gbufA -> [w1: poll B(t), issue DMA->hlsB] ->
//               raw lgkm-barrier -> tailA -> __syncthreads -> flagA(t+1)
//   phase B(t): same with A(t+1) polled/issued into hlsA.
// Each DMA's latency is hidden under the same phase's tail + full-drain sync.
// ---------------------------------------------------------------------------
__global__ __launch_bounds__(256, 1) void lstm_scan(
    const unsigned short* __restrict__ xw, const float* __restrict__ h0,
    unsigned short* __restrict__ hrot,     // [TT+1][64][1024] bf16 rotating
    const short* __restrict__ upk,
    float* __restrict__ y, int* __restrict__ flg)   // [TT+1][4][64]
{
    __shared__ unsigned short hlsA[16 * 1032 + 8];
    __shared__ unsigned short hlsB[16 * 1032 + 8];
    __shared__ float gbufA[4][16][20];
    __shared__ float gbufB[4][16][20];

    const int tid = threadIdx.x;
    const int lane = tid & 63;
    const int gi = tid >> 6;              // wave = gate
    const int z  = blockIdx.x >> 6;
    const int ub = blockIdx.x & 63;
    const int mzA = z * 2, mzB = z * 2 + 1;
    const int r0A = mzA << 4, r0B = mzB << 4;
    const int u0 = ub << 4;

    const short* __restrict__ bsrc =
        upk + ((size_t)(gi * 64 + ub) * 32) * 512 + (size_t)lane * 8;
    short8 bfr[32];
#pragma unroll
    for (int kb = 0; kb < 32; ++kb)
        bfr[kb] = *reinterpret_cast<const short8*>(bsrc + (size_t)kb * 512);

    const int aoff = (lane & 15) * 1032 + (lane >> 4) * 8;
    const int trow = tid >> 4, tcol = tid & 15;

    float h_ownA = h0[u0 + tcol];
    float h_ownB = h_ownA;

    // prologue: wave 1 stages both chains' slot-0 tiles (h0, kernel-boundary
    // visible), then a full sync (drains the DMA for everyone).
    if (gi == 1) {
#pragma unroll
        for (int p = 0; p < 32; ++p) {
            int row = p >> 1, half = p & 1;
            __builtin_amdgcn_global_load_lds(
                (const void*)(hrot + (size_t)r0A * UU + (size_t)row * 1024
                              + half * 512 + (size_t)lane * 8),
                (void*)&hlsA[row * 1032 + half * 512], 16, 0, 16);
            __builtin_amdgcn_global_load_lds(
                (const void*)(hrot + (size_t)r0B * UU + (size_t)row * 1024
                              + half * 512 + (size_t)lane * 8),
                (void*)&hlsB[row * 1032 + half * 512], 16, 0, 16);
        }
    }
    __syncthreads();

    for (int t = 0; t < TT; ++t) {
        PHASE(mzA, r0A, hlsA, gbufA, h_ownA, mzB, hlsB, (t >= 1), t);
        PHASE(mzB, r0B, hlsB, gbufB, h_ownB, mzA, hlsA, (t + 1 < TT), t + 1);
    }
}

// ---------------------------------------------------------------------------
extern "C" void kernel_launch(void* const* d_in, const int* in_sizes, int n_in,
                              void* d_out, int out_size, void* d_ws, size_t ws_size,
                              hipStream_t stream)
{
    const float* x  = (const float*)d_in[0];
    const float* fw = (const float*)d_in[1];
    const float* fu = (const float*)d_in[2];
    const float* fb = (const float*)d_in[3];
    const float* iw = (const float*)d_in[4];
    const float* iu = (const float*)d_in[5];
    const float* ib = (const float*)d_in[6];
    const float* cw = (const float*)d_in[7];
    const float* cu = (const float*)d_in[8];
    const float* cb = (const float*)d_in[9];
    const float* ow = (const float*)d_in[10];
    const float* ou = (const float*)d_in[11];
    const float* ob = (const float*)d_in[12];
    const float* h0 = (const float*)d_in[13];
    float* y = (float*)d_out;

    const size_t xw_elems = (size_t)TT * BB * 4 * UU;       // 134,217,728
    const size_t pk_elems = (size_t)4 * 1024 * 1024;        // shorts per packed W
    const size_t hrot_elems = (size_t)(TT + 1) * BB * UU;

    char* wsb = (char*)d_ws;
    unsigned short* xw = (unsigned short*)wsb;
    short* upk = (short*)(wsb + xw_elems * 2);
    short* wpk = upk + pk_elems;
    unsigned short* hrot = (unsigned short*)(wpk + pk_elems);
    int* flg = (int*)(hrot + hrot_elems);

    pack_w<<<2048, 256, 0, stream>>>(fu, iu, cu, ou, upk);
    pack_w<<<2048, 256, 0, stream>>>(fw, iw, cw, ow, wpk);
    init_hbf<<<256, 256, 0, stream>>>(h0, hrot);
    gemm_xw<<<dim3(32, 256), 256, 0, stream>>>(x, wpk, fb, ib, cb, ob, xw);
    hipMemsetAsync(flg, 0, (size_t)(TT + 1) * 4 * 64 * sizeof(int), stream);

    lstm_scan<<<128, 256, 0, stream>>>(xw, h0, hrot, upk, y, flg);
}